// Round 1
// baseline (105.575 us; speedup 1.0000x reference)
//
#include <hip/hip_runtime.h>
#include <math.h>

#define TPB 256
#define TILE 256          // target points staged per LDS tile

// Kernel 1: partial min/max of pairwise squared distances.
// grid = (N/TPB, S). Block (bx, s) handles source points [bx*TPB, bx*TPB+TPB)
// against target split s (chunk = M/S targets), tiled through LDS.
// part layout: [4][S][N]  (comp: 0=min_start 1=max_start 2=min_end 3=max_end)
__global__ __launch_bounds__(TPB) void k1_partial_minmax(
    const float* __restrict__ source,
    const float* __restrict__ target,
    const float* __restrict__ trans_m,
    float* __restrict__ part,
    int N, int M, int T, int S)
{
    const int chunk = M / S;
    const int i = blockIdx.x * TPB + threadIdx.x;
    const int s = blockIdx.y;

    __shared__ float tgt[TILE * 3];

    // source point and denoised point (source - trans_m[T-1])
    const float sx = source[i * 3 + 0];
    const float sy = source[i * 3 + 1];
    const float sz = source[i * 3 + 2];
    const long teoff = (long)(T - 1) * N * 3 + (long)i * 3;
    const float ex = sx - trans_m[teoff + 0];
    const float ey = sy - trans_m[teoff + 1];
    const float ez = sz - trans_m[teoff + 2];

    float mins = 3.402823e38f, maxs = -3.402823e38f;
    float mine = 3.402823e38f, maxe = -3.402823e38f;

    const int t_begin = s * chunk;
    const int t_end   = t_begin + chunk;

    for (int t0 = t_begin; t0 < t_end; t0 += TILE) {
        __syncthreads();   // protect LDS before overwrite
        // coalesced flat copy of TILE target points (AoS)
        for (int k = threadIdx.x; k < TILE * 3; k += TPB)
            tgt[k] = target[(long)t0 * 3 + k];
        __syncthreads();

        #pragma unroll 4
        for (int j = 0; j < TILE; ++j) {
            const float tx = tgt[j * 3 + 0];
            const float ty = tgt[j * 3 + 1];
            const float tz = tgt[j * 3 + 2];
            float dx = sx - tx, dy = sy - ty, dz = sz - tz;
            float ds = dx * dx + dy * dy + dz * dz;
            mins = fminf(mins, ds);
            maxs = fmaxf(maxs, ds);
            dx = ex - tx; dy = ey - ty; dz = ez - tz;
            float de = dx * dx + dy * dy + dz * dz;
            mine = fminf(mine, de);
            maxe = fmaxf(maxe, de);
        }
    }

    part[(0 * S + s) * (long)N + i] = mins;
    part[(1 * S + s) * (long)N + i] = maxs;
    part[(2 * S + s) * (long)N + i] = mine;
    part[(3 * S + s) * (long)N + i] = maxe;
}

// Kernel 2: reduce partials per point, compute per-point loss, block-sum.
__global__ __launch_bounds__(TPB) void k2_loss(
    const float* __restrict__ part,
    const float* __restrict__ label,
    const float* __restrict__ path_m,
    const float* __restrict__ path_maxprob_m,
    float* __restrict__ blocksums,
    int N, int S, int T)
{
    const int i = blockIdx.x * TPB + threadIdx.x;

    float mins = 3.402823e38f, maxs = -3.402823e38f;
    float mine = 3.402823e38f, maxe = -3.402823e38f;
    for (int s = 0; s < S; ++s) {
        mins = fminf(mins, part[(0 * S + s) * (long)N + i]);
        maxs = fmaxf(maxs, part[(1 * S + s) * (long)N + i]);
        mine = fminf(mine, part[(2 * S + s) * (long)N + i]);
        maxe = fmaxf(maxe, part[(3 * S + s) * (long)N + i]);
    }

    const float p = 0.002f, L0 = 0.4f, lam = 0.05f, gamma = 0.99f;
    const float loss_start = 0.99f * mins + 0.01f * maxs;
    const float loss_end   = 0.99f * mine + 0.01f * maxe;
    const float loss_dt    = loss_end - loss_start;
    const float d = fminf(loss_end / L0, 1.0f);
    const float l = expf(-label[i]);
    const float reward_end = -p * path_m[(long)(T - 1) * N + i]
                             - (d + lam * l) * loss_dt;

    // discounted return scan, t = T-1 .. 0:  R = g*R + lp*(r+0.02); L -= R
    float R = 0.0f, L = 0.0f;
    for (int t = T - 1; t >= 0; --t) {
        const float r  = (t == T - 1) ? reward_end
                                      : (-p * path_m[(long)t * N + i]);
        const float lp = logf(path_maxprob_m[(long)t * N + i]);
        R = gamma * R + lp * (r + 0.02f);
        L -= R;
    }
    float v = L / (float)T;   // per-point loss

    // block reduction (4 waves of 64)
    for (int off = 32; off > 0; off >>= 1) v += __shfl_down(v, off, 64);
    __shared__ float red[TPB / 64];
    const int wid = threadIdx.x >> 6, lane = threadIdx.x & 63;
    if (lane == 0) red[wid] = v;
    __syncthreads();
    if (threadIdx.x == 0) {
        float t = 0.0f;
        #pragma unroll
        for (int w = 0; w < TPB / 64; ++w) t += red[w];
        blocksums[blockIdx.x] = t;
    }
}

// Kernel 3: final reduce of block sums -> mean
__global__ void k3_final(const float* __restrict__ blocksums,
                         float* __restrict__ out, int nb, int N)
{
    float v = (threadIdx.x < nb) ? blocksums[threadIdx.x] : 0.0f;
    for (int off = 32; off > 0; off >>= 1) v += __shfl_down(v, off, 64);
    if (threadIdx.x == 0) out[0] = v / (float)N;
}

extern "C" void kernel_launch(void* const* d_in, const int* in_sizes, int n_in,
                              void* d_out, int out_size, void* d_ws, size_t ws_size,
                              hipStream_t stream) {
    const float* source = (const float*)d_in[0];
    const float* target = (const float*)d_in[1];
    const float* label  = (const float*)d_in[2];
    const float* trans  = (const float*)d_in[3];
    const float* path   = (const float*)d_in[4];
    const float* pmax   = (const float*)d_in[5];

    const int N = in_sizes[0] / 3;          // 8192
    const int M = in_sizes[1] / 3;          // 8192
    const int T = in_sizes[3] / (N * 3);    // 8
    const int nbx = N / TPB;                // 32

    // choose target-dim splits S (power of 2) so partials fit in d_ws
    int S = 32;
    while (S > 1 && (size_t)(4 * (size_t)S * N + nbx) * sizeof(float) > ws_size)
        S >>= 1;

    float* part      = (float*)d_ws;             // [4][S][N]
    float* blocksums = part + (size_t)4 * S * N; // [nbx]

    k1_partial_minmax<<<dim3(nbx, S), TPB, 0, stream>>>(
        source, target, trans, part, N, M, T, S);
    k2_loss<<<nbx, TPB, 0, stream>>>(
        part, label, path, pmax, blocksums, N, S, T);
    k3_final<<<1, 64, 0, stream>>>(blocksums, (float*)d_out, nbx, N);
}

// Round 2
// 105.169 us; speedup vs baseline: 1.0039x; 1.0039x over previous
//
#include <hip/hip_runtime.h>
#include <math.h>

#define TPB 256
#define TILE 128          // target points staged per LDS tile

// Kernel 1: partial min/max of pairwise squared distances, dot-product form.
// dist(s,t) = |s|^2 + (|t|^2 - 2 s.t). We track min/max of a = |t|^2 - 2 s.t
// and add |s|^2 in the epilogue (monotone shift commutes with min/max).
// grid = (N/TPB, S). Block (bx, s) handles source points [bx*TPB, ...)
// against target chunk s (M/S targets), tiled through LDS as float4{x,y,z,|t|^2}.
// part layout: [4][S][N]  (comp: 0=min_start 1=max_start 2=min_end 3=max_end)
__global__ __launch_bounds__(TPB) void k1_partial_minmax(
    const float* __restrict__ source,
    const float* __restrict__ target,
    const float* __restrict__ trans_m,
    float* __restrict__ part,
    int N, int M, int T, int S)
{
    const int chunk = M / S;
    const int i = blockIdx.x * TPB + threadIdx.x;
    const int s = blockIdx.y;

    __shared__ float4 tgt[TILE];

    // source point and denoised point (source - trans_m[T-1])
    const float sx = source[i * 3 + 0];
    const float sy = source[i * 3 + 1];
    const float sz = source[i * 3 + 2];
    const long teoff = (long)(T - 1) * N * 3 + (long)i * 3;
    const float ex = sx - trans_m[teoff + 0];
    const float ey = sy - trans_m[teoff + 1];
    const float ez = sz - trans_m[teoff + 2];

    const float ss = fmaf(sx, sx, fmaf(sy, sy, sz * sz));
    const float ee = fmaf(ex, ex, fmaf(ey, ey, ez * ez));
    const float vsx = -2.0f * sx, vsy = -2.0f * sy, vsz = -2.0f * sz;
    const float vex = -2.0f * ex, vey = -2.0f * ey, vez = -2.0f * ez;

    float mins = 3.402823e38f, maxs = -3.402823e38f;
    float mine = 3.402823e38f, maxe = -3.402823e38f;

    const int t_begin = s * chunk;
    const int t_end   = t_begin + chunk;

    for (int t0 = t_begin; t0 < t_end; t0 += TILE) {
        __syncthreads();   // protect LDS before overwrite
        for (int j = threadIdx.x; j < TILE; j += TPB) {
            const float tx = target[(long)(t0 + j) * 3 + 0];
            const float ty = target[(long)(t0 + j) * 3 + 1];
            const float tz = target[(long)(t0 + j) * 3 + 2];
            const float q  = fmaf(tx, tx, fmaf(ty, ty, tz * tz));
            tgt[j] = make_float4(tx, ty, tz, q);
        }
        __syncthreads();

        #pragma unroll 8
        for (int j = 0; j < TILE; ++j) {
            const float4 t = tgt[j];
            float a = fmaf(vsx, t.x, t.w);
            a = fmaf(vsy, t.y, a);
            a = fmaf(vsz, t.z, a);
            mins = fminf(mins, a);
            maxs = fmaxf(maxs, a);
            float b = fmaf(vex, t.x, t.w);
            b = fmaf(vey, t.y, b);
            b = fmaf(vez, t.z, b);
            mine = fminf(mine, b);
            maxe = fmaxf(maxe, b);
        }
    }

    part[(0 * S + s) * (long)N + i] = mins + ss;
    part[(1 * S + s) * (long)N + i] = maxs + ss;
    part[(2 * S + s) * (long)N + i] = mine + ee;
    part[(3 * S + s) * (long)N + i] = maxe + ee;
}

// Kernel 2: reduce partials per point, compute per-point loss, block-sum.
__global__ __launch_bounds__(TPB) void k2_loss(
    const float* __restrict__ part,
    const float* __restrict__ label,
    const float* __restrict__ path_m,
    const float* __restrict__ path_maxprob_m,
    float* __restrict__ blocksums,
    int N, int S, int T)
{
    const int i = blockIdx.x * TPB + threadIdx.x;

    float mins = 3.402823e38f, maxs = -3.402823e38f;
    float mine = 3.402823e38f, maxe = -3.402823e38f;
    for (int s = 0; s < S; ++s) {
        mins = fminf(mins, part[(0 * S + s) * (long)N + i]);
        maxs = fmaxf(maxs, part[(1 * S + s) * (long)N + i]);
        mine = fminf(mine, part[(2 * S + s) * (long)N + i]);
        maxe = fmaxf(maxe, part[(3 * S + s) * (long)N + i]);
    }

    const float p = 0.002f, L0 = 0.4f, lam = 0.05f, gamma = 0.99f;
    const float loss_start = 0.99f * mins + 0.01f * maxs;
    const float loss_end   = 0.99f * mine + 0.01f * maxe;
    const float loss_dt    = loss_end - loss_start;
    const float d = fminf(loss_end / L0, 1.0f);
    const float l = expf(-label[i]);
    const float reward_end = -p * path_m[(long)(T - 1) * N + i]
                             - (d + lam * l) * loss_dt;

    // discounted return scan, t = T-1 .. 0:  R = g*R + lp*(r+0.02); L -= R
    float R = 0.0f, L = 0.0f;
    for (int t = T - 1; t >= 0; --t) {
        const float r  = (t == T - 1) ? reward_end
                                      : (-p * path_m[(long)t * N + i]);
        const float lp = logf(path_maxprob_m[(long)t * N + i]);
        R = gamma * R + lp * (r + 0.02f);
        L -= R;
    }
    float v = L / (float)T;   // per-point loss

    // block reduction (4 waves of 64)
    for (int off = 32; off > 0; off >>= 1) v += __shfl_down(v, off, 64);
    __shared__ float red[TPB / 64];
    const int wid = threadIdx.x >> 6, lane = threadIdx.x & 63;
    if (lane == 0) red[wid] = v;
    __syncthreads();
    if (threadIdx.x == 0) {
        float t = 0.0f;
        #pragma unroll
        for (int w = 0; w < TPB / 64; ++w) t += red[w];
        blocksums[blockIdx.x] = t;
    }
}

// Kernel 3: final reduce of block sums -> mean
__global__ void k3_final(const float* __restrict__ blocksums,
                         float* __restrict__ out, int nb, int N)
{
    float v = (threadIdx.x < nb) ? blocksums[threadIdx.x] : 0.0f;
    for (int off = 32; off > 0; off >>= 1) v += __shfl_down(v, off, 64);
    if (threadIdx.x == 0) out[0] = v / (float)N;
}

extern "C" void kernel_launch(void* const* d_in, const int* in_sizes, int n_in,
                              void* d_out, int out_size, void* d_ws, size_t ws_size,
                              hipStream_t stream) {
    const float* source = (const float*)d_in[0];
    const float* target = (const float*)d_in[1];
    const float* label  = (const float*)d_in[2];
    const float* trans  = (const float*)d_in[3];
    const float* path   = (const float*)d_in[4];
    const float* pmax   = (const float*)d_in[5];

    const int N = in_sizes[0] / 3;          // 8192
    const int M = in_sizes[1] / 3;          // 8192
    const int T = in_sizes[3] / (N * 3);    // 8
    const int nbx = N / TPB;                // 32

    // choose target-dim splits S (power of 2) so partials fit in d_ws
    // and chunk = M/S stays a multiple of TILE
    int S = 64;
    while (S > 1 && ((size_t)(4 * (size_t)S * N + nbx) * sizeof(float) > ws_size
                     || (M / S) < TILE))
        S >>= 1;

    float* part      = (float*)d_ws;             // [4][S][N]
    float* blocksums = part + (size_t)4 * S * N; // [nbx]

    k1_partial_minmax<<<dim3(nbx, S), TPB, 0, stream>>>(
        source, target, trans, part, N, M, T, S);
    k2_loss<<<nbx, TPB, 0, stream>>>(
        part, label, path, pmax, blocksums, N, S, T);
    k3_final<<<1, 64, 0, stream>>>(blocksums, (float*)d_out, nbx, N);
}

// Round 3
// 88.256 us; speedup vs baseline: 1.1962x; 1.1916x over previous
//
#include <hip/hip_runtime.h>
#include <math.h>

#define TPB 256
#define TILE 128          // target points staged per LDS tile

// Kernel 1: partial min/max of pairwise squared distances, dot-product form.
// dist(s,t) = |s|^2 + (|t|^2 - 2 s.t). We track min/max of a = |t|^2 - 2 s.t
// and add |s|^2 in the epilogue (monotone shift commutes with min/max).
// grid = (N/TPB, S). Block (bx, s) handles source points [bx*TPB, ...)
// against target chunk s (M/S targets), tiled through LDS as float4{x,y,z,|t|^2}.
// part layout: [S][N] of float4 {min_start, max_start, min_end, max_end}
__global__ __launch_bounds__(TPB) void k1_partial_minmax(
    const float* __restrict__ source,
    const float* __restrict__ target,
    const float* __restrict__ trans_m,
    float4* __restrict__ part,
    int* __restrict__ counter,
    int N, int M, int T, int S)
{
    // zero the k2 completion counter (runs before k2 in stream order)
    if (blockIdx.x == 0 && blockIdx.y == 0 && threadIdx.x == 0) *counter = 0;

    const int chunk = M / S;
    const int i = blockIdx.x * TPB + threadIdx.x;
    const int s = blockIdx.y;

    __shared__ float4 tgt[TILE];

    // source point and denoised point (source - trans_m[T-1])
    const float sx = source[i * 3 + 0];
    const float sy = source[i * 3 + 1];
    const float sz = source[i * 3 + 2];
    const long teoff = (long)(T - 1) * N * 3 + (long)i * 3;
    const float ex = sx - trans_m[teoff + 0];
    const float ey = sy - trans_m[teoff + 1];
    const float ez = sz - trans_m[teoff + 2];

    const float ss = fmaf(sx, sx, fmaf(sy, sy, sz * sz));
    const float ee = fmaf(ex, ex, fmaf(ey, ey, ez * ez));
    const float vsx = -2.0f * sx, vsy = -2.0f * sy, vsz = -2.0f * sz;
    const float vex = -2.0f * ex, vey = -2.0f * ey, vez = -2.0f * ez;

    float mins = 3.402823e38f, maxs = -3.402823e38f;
    float mine = 3.402823e38f, maxe = -3.402823e38f;

    const int t_begin = s * chunk;
    const int t_end   = t_begin + chunk;

    for (int t0 = t_begin; t0 < t_end; t0 += TILE) {
        __syncthreads();   // protect LDS before overwrite
        for (int j = threadIdx.x; j < TILE; j += TPB) {
            const float tx = target[(long)(t0 + j) * 3 + 0];
            const float ty = target[(long)(t0 + j) * 3 + 1];
            const float tz = target[(long)(t0 + j) * 3 + 2];
            const float q  = fmaf(tx, tx, fmaf(ty, ty, tz * tz));
            tgt[j] = make_float4(tx, ty, tz, q);
        }
        __syncthreads();

        #pragma unroll 8
        for (int j = 0; j < TILE; ++j) {
            const float4 t = tgt[j];
            float a = fmaf(vsx, t.x, t.w);
            a = fmaf(vsy, t.y, a);
            a = fmaf(vsz, t.z, a);
            mins = fminf(mins, a);
            maxs = fmaxf(maxs, a);
            float b = fmaf(vex, t.x, t.w);
            b = fmaf(vey, t.y, b);
            b = fmaf(vez, t.z, b);
            mine = fminf(mine, b);
            maxe = fmaxf(maxe, b);
        }
    }

    part[(long)s * N + i] = make_float4(mins + ss, maxs + ss, mine + ee, maxe + ee);
}

// Kernel 2 (fused with final reduce): reduce partials per point, per-point
// loss + T-step scan, block-sum, then last-done block sums the block sums
// (deterministic: single thread, fixed order) and writes mean to d_out.
__global__ __launch_bounds__(TPB) void k2_loss(
    const float4* __restrict__ part,
    const float* __restrict__ label,
    const float* __restrict__ path_m,
    const float* __restrict__ path_maxprob_m,
    float* __restrict__ blocksums,
    int* __restrict__ counter,
    float* __restrict__ out,
    int N, int S, int T)
{
    const int i = blockIdx.x * TPB + threadIdx.x;

    float mins = 3.402823e38f, maxs = -3.402823e38f;
    float mine = 3.402823e38f, maxe = -3.402823e38f;
    #pragma unroll 4
    for (int s = 0; s < S; ++s) {
        const float4 v = part[(long)s * N + i];
        mins = fminf(mins, v.x);
        maxs = fmaxf(maxs, v.y);
        mine = fminf(mine, v.z);
        maxe = fmaxf(maxe, v.w);
    }

    const float p = 0.002f, L0 = 0.4f, lam = 0.05f, gamma = 0.99f;
    const float loss_start = 0.99f * mins + 0.01f * maxs;
    const float loss_end   = 0.99f * mine + 0.01f * maxe;
    const float loss_dt    = loss_end - loss_start;
    const float d = fminf(loss_end / L0, 1.0f);
    const float l = expf(-label[i]);
    const float reward_end = -p * path_m[(long)(T - 1) * N + i]
                             - (d + lam * l) * loss_dt;

    // discounted return scan, t = T-1 .. 0:  R = g*R + lp*(r+0.02); L -= R
    float R = 0.0f, L = 0.0f;
    for (int t = T - 1; t >= 0; --t) {
        const float r  = (t == T - 1) ? reward_end
                                      : (-p * path_m[(long)t * N + i]);
        const float lp = logf(path_maxprob_m[(long)t * N + i]);
        R = gamma * R + lp * (r + 0.02f);
        L -= R;
    }
    float v = L / (float)T;   // per-point loss

    // block reduction (4 waves of 64)
    for (int off = 32; off > 0; off >>= 1) v += __shfl_down(v, off, 64);
    __shared__ float red[TPB / 64];
    __shared__ bool amLast;
    const int wid = threadIdx.x >> 6, lane = threadIdx.x & 63;
    if (lane == 0) red[wid] = v;
    __syncthreads();
    if (threadIdx.x == 0) {
        float t = 0.0f;
        #pragma unroll
        for (int w = 0; w < TPB / 64; ++w) t += red[w];
        blocksums[blockIdx.x] = t;
        __threadfence();                       // publish blocksum device-wide
        const int old = atomicAdd(counter, 1); // device-scope by default
        amLast = (old == (int)gridDim.x - 1);
    }
    __syncthreads();
    if (amLast && threadIdx.x == 0) {
        __threadfence();                       // order reads after counter
        float tot = 0.0f;
        for (int b = 0; b < (int)gridDim.x; ++b)
            tot += ((volatile float*)blocksums)[b];
        out[0] = tot / (float)N;
    }
}

extern "C" void kernel_launch(void* const* d_in, const int* in_sizes, int n_in,
                              void* d_out, int out_size, void* d_ws, size_t ws_size,
                              hipStream_t stream) {
    const float* source = (const float*)d_in[0];
    const float* target = (const float*)d_in[1];
    const float* label  = (const float*)d_in[2];
    const float* trans  = (const float*)d_in[3];
    const float* path   = (const float*)d_in[4];
    const float* pmax   = (const float*)d_in[5];

    const int N = in_sizes[0] / 3;          // 8192
    const int M = in_sizes[1] / 3;          // 8192
    const int T = in_sizes[3] / (N * 3);    // 8
    const int nbx = N / TPB;                // 32

    // choose target-dim splits S (power of 2) so partials fit in d_ws
    // and chunk = M/S stays a multiple of TILE
    int S = 64;
    while (S > 1 && ((size_t)S * N * sizeof(float4)
                         + (size_t)(nbx + 1) * sizeof(float) > ws_size
                     || (M / S) < TILE))
        S >>= 1;

    float4* part     = (float4*)d_ws;                 // [S][N] float4
    float* blocksums = (float*)(part + (size_t)S * N); // [nbx]
    int*   counter   = (int*)(blocksums + nbx);        // [1]

    k1_partial_minmax<<<dim3(nbx, S), TPB, 0, stream>>>(
        source, target, trans, part, counter, N, M, T, S);
    k2_loss<<<nbx, TPB, 0, stream>>>(
        part, label, path, pmax, blocksums, counter, (float*)d_out, N, S, T);
}